// Round 6
// baseline (188.769 us; speedup 1.0000x reference)
//
#include <hip/hip_runtime.h>
#include <math.h>

// CapsuleLayer dynamic routing, fp32 in/out. B=256, I=2048, K=8, J=10, D=16.
// R6: single-staged 8-i chunks (28 KB LDS) -> 3+ blocks/CU resident (R5 was 2),
// grid (256,4)=1024 blocks = exactly 4 waves/SIMD of work. Block = 4 waves =
// 4 b-tiles (64 b) sharing one W tile in LDS. Keep-U register scheme (no VGPR cap
// -- R4 lesson: caps cause scratch spill). Per-wave partial chunks, no atomics.
// mfma_f32_16x16x32_bf16: C/D col=lane&15=b, row=(lane>>4)*4+reg=d.
// Round 1 packs 4 i's into K=32 (kc=q*8+k -> i_local=q); rounds 2/3 use kc 0..7.
// Routing logits are linear in accumulated v (round 3 uses v1+v2).
//
// ws: vT f32[40960] | p f32[16*256*2560] | xTb bf16[I*B*K] | Wb bf16[J*I*D*K] (~56 MB)

#define BB 256
#define II 2048
#define KK 8
#define JJ 10
#define DD 16
#define NCH 256   // i-chunks (8 i each)

typedef __attribute__((ext_vector_type(4))) float f32x4;
typedef __attribute__((ext_vector_type(8))) short short8;

__device__ __forceinline__ short f2bf(float f) {
    union { float f; unsigned u; } v; v.f = f;
    unsigned r = v.u + 0x7FFFu + ((v.u >> 16) & 1u);   // RNE
    return (short)(r >> 16);
}

// W fp32 [j,i,d,k] -> Wb bf16 same layout (k contiguous = A-frag rows).
__global__ __launch_bounds__(256) void cast_w_kernel(const float* __restrict__ W,
                                                     short* __restrict__ Wb) {
    const int idx = blockIdx.x * blockDim.x + threadIdx.x;
    const float4* src = (const float4*)(W + (size_t)idx * 8);
    const float4 a = src[0], b = src[1];
    short8 o;
    o[0] = f2bf(a.x); o[1] = f2bf(a.y); o[2] = f2bf(a.z); o[3] = f2bf(a.w);
    o[4] = f2bf(b.x); o[5] = f2bf(b.y); o[6] = f2bf(b.z); o[7] = f2bf(b.w);
    *(short8*)(Wb + (size_t)idx * 8) = o;
}

// x fp32 [b,i,k] -> xTb bf16 [i,b,k], LDS-tiled, coalesced both sides.
__global__ __launch_bounds__(256) void trans_x_kernel(const float* __restrict__ x,
                                                      short* __restrict__ xTb) {
    __shared__ float4 tile[8 * 66];
    const int t = threadIdx.x;
    const int b0 = blockIdx.y * 32, i0 = blockIdx.x * 8;
    {
        const int lb = t >> 3, li = t & 7;
        const float4* src = (const float4*)(x + ((b0 + lb) * II + (i0 + li)) * KK);
        tile[li * 66 + lb * 2 + 0] = src[0];
        tile[li * 66 + lb * 2 + 1] = src[1];
    }
    __syncthreads();
    {
        const int ri = t >> 5, rb = t & 31;
        const float4 p0 = tile[ri * 66 + rb * 2 + 0];
        const float4 p1 = tile[ri * 66 + rb * 2 + 1];
        short8 o;
        o[0] = f2bf(p0.x); o[1] = f2bf(p0.y); o[2] = f2bf(p0.z); o[3] = f2bf(p0.w);
        o[4] = f2bf(p1.x); o[5] = f2bf(p1.y); o[6] = f2bf(p1.z); o[7] = f2bf(p1.w);
        *(short8*)(xTb + ((size_t)(i0 + ri) * BB + (b0 + rb)) * KK) = o;
    }
}

// LDS: W at j*1024 + il*128 + d*8 (shorts); x at 10240 + il*512 + b*8. 14336 shorts.
#define LBUF 14336

// One routing round. grid (256, 4), block 256 (4 waves = 4 b-tiles), 8 i per block.
// Partials p[btile(16)][chunk(256)][j*64 + lane] (f32x4 per lane).
template <int USE_C>
__global__ __launch_bounds__(256) void round_mfma(
    const short* __restrict__ xTb, const short* __restrict__ Wb,
    const float* __restrict__ vT, float* __restrict__ p)
{
    __shared__ short Ls[LBUF];
    const int t = threadIdx.x;
    const int lane = t & 63, wv = t >> 6;
    const int col = lane & 15, q = lane >> 4;
    const int b0 = blockIdx.y * 64;
    const int bl = wv * 16 + col;          // b within block for this wave's tile
    const int i0 = blockIdx.x * 8;

    // stage 28 segments of 1024 B (20 W halves + 8 x rows), 7 per wave
#pragma unroll
    for (int n = 0; n < 7; ++n) {
        const int s = wv + n * 4;
        const short* src;
        int dst;
        if (s < 20) {
            src = Wb + ((size_t)((s >> 1) * II + i0) * DD) * KK + (s & 1) * 512;
            dst = (s >> 1) * 1024 + (s & 1) * 512;
        } else {
            src = xTb + ((size_t)(i0 + (s - 20)) * BB + b0) * KK;
            dst = 10240 + (s - 20) * 512;
        }
        *(short8*)(&Ls[dst + lane * 8]) = *(const short8*)(src + lane * 8);
    }

    f32x4 sfrag[JJ];
#pragma unroll
    for (int j = 0; j < JJ; ++j) sfrag[j] = (f32x4){0.f, 0.f, 0.f, 0.f};

    if (USE_C) {
        float vfrag[JJ][4];
#pragma unroll
        for (int j = 0; j < JJ; ++j)
#pragma unroll
            for (int r = 0; r < 4; ++r)
                vfrag[j][r] = vT[(j * DD + q * 4 + r) * BB + b0 + bl];
        __syncthreads();

        const short8 z = (short8){0, 0, 0, 0, 0, 0, 0, 0};
        for (int il = 0; il < 8; ++il) {
            short8 Bf = z;
            if (q == 0) Bf = *(const short8*)(&Ls[10240 + il * 512 + bl * 8]);
            f32x4 U[JJ];
            float Lg[JJ];
#pragma unroll
            for (int j = 0; j < JJ; ++j) {
                short8 Aj = z;
                if (q == 0) Aj = *(const short8*)(&Ls[j * 1024 + il * 128 + col * 8]);
                U[j] = __builtin_amdgcn_mfma_f32_16x16x32_bf16(
                    Aj, Bf, (f32x4){0.f, 0.f, 0.f, 0.f}, 0, 0, 0);
                Lg[j] = vfrag[j][0] * U[j][0] + vfrag[j][1] * U[j][1]
                      + vfrag[j][2] * U[j][2] + vfrag[j][3] * U[j][3];
            }
#pragma unroll
            for (int j = 0; j < JJ; ++j) {   // reduce over the 4 d-quads (same b col)
                Lg[j] += __shfl_xor(Lg[j], 16, 64);
                Lg[j] += __shfl_xor(Lg[j], 32, 64);
            }
            float sum = 0.f;   // |logit| is O(1): no max-subtraction needed
#pragma unroll
            for (int j = 0; j < JJ; ++j) { Lg[j] = __expf(Lg[j]); sum += Lg[j]; }
            const float inv = __builtin_amdgcn_rcpf(sum);
#pragma unroll
            for (int j = 0; j < JJ; ++j) {
                const float c = Lg[j] * inv;
#pragma unroll
                for (int r = 0; r < 4; ++r) sfrag[j][r] += c * U[j][r];
            }
        }
    } else {
        __syncthreads();
        // round 1: sum_i U. Pack 4 i's per MFMA: kc = q*8 + k -> i_local = q.
#pragma unroll
        for (int g = 0; g < 2; ++g) {
            const int il = g * 4 + q;
            const short8 Bf = *(const short8*)(&Ls[10240 + il * 512 + bl * 8]);
#pragma unroll
            for (int j = 0; j < JJ; ++j) {
                const short8 Aj = *(const short8*)(&Ls[j * 1024 + il * 128 + col * 8]);
                sfrag[j] = __builtin_amdgcn_mfma_f32_16x16x32_bf16(Aj, Bf, sfrag[j], 0, 0, 0);
            }
        }
    }

    // epilogue: wave-private partial chunk, 10 coalesced 16B stores
    float* pp = p + ((size_t)(blockIdx.y * 4 + wv) * NCH + blockIdx.x) * (JJ * 256);
#pragma unroll
    for (int j = 0; j < JJ; ++j)
        *(f32x4*)(pp + (j * 64 + lane) * 4) = sfrag[j];
}

// Fused reduce + squash. grid (10 j, 16 bt), block 256 (t = d*16 + bc).
// p element (j,d,bc) lives at j*256 + lane*4 + r, lane=(d>>2)*16+bc, r=d&3.
// MODE 0: vT = squash(scale*s)   MODE 1: vT += squash(s)   MODE 2: out = squash(s)
template <int MODE>
__global__ __launch_bounds__(256) void rs_kernel(const float* __restrict__ p,
                                                 float* __restrict__ vT,
                                                 float* __restrict__ out, float scale) {
    __shared__ float red[256];
    __shared__ float cf[16];
    const int t = threadIdx.x;
    const int j = blockIdx.x, bt = blockIdx.y;
    const int d = t >> 4, bc = t & 15;
    const int lane = (d >> 2) * 16 + bc, r = d & 3;

    const float* pp = p + (size_t)bt * NCH * (JJ * 256) + j * 256 + lane * 4 + r;
    float sum = 0.f;
#pragma unroll 8
    for (int ch = 0; ch < NCH; ++ch) sum += pp[(size_t)ch * (JJ * 256)];
    const float s = sum * scale;

    red[t] = s;
    __syncthreads();
    if (t < 16) {
        float ss = 0.f;
#pragma unroll
        for (int dd = 0; dd < DD; ++dd) {
            const float v = red[dd * 16 + t];
            ss += v * v;
        }
        cf[t] = ss / (1.f + ss) / sqrtf(ss + 1e-7f);
    }
    __syncthreads();
    const float v = cf[bc] * s;
    if (MODE == 0) vT[(j * DD + d) * BB + bt * 16 + bc] = v;
    if (MODE == 1) vT[(j * DD + d) * BB + bt * 16 + bc] += v;
    if (MODE == 2) out[((bt * 16 + bc) * JJ + j) * DD + d] = v;
}

// ---------------- fallback path (round-1 passing kernel, 365us) ----------------
#define IT_OLD 32
#define BT_OLD 16

__global__ __launch_bounds__(256) void zero_kernel(float* __restrict__ p, int n) {
    int idx = blockIdx.x * blockDim.x + threadIdx.x;
    if (idx < n) p[idx] = 0.f;
}

__global__ __launch_bounds__(256) void squash_old(float* __restrict__ s_acc,
                                                  float* __restrict__ dst, float scale,
                                                  int add_to_dst, int zero_src) {
    int idx = blockIdx.x * blockDim.x + threadIdx.x;
    if (idx >= BB * JJ) return;
    float s[DD];
    float ss = 0.f;
#pragma unroll
    for (int d = 0; d < DD; ++d) {
        s[d] = s_acc[idx * DD + d] * scale;
        ss += s[d] * s[d];
    }
    const float coef = ss / (1.f + ss) / sqrtf(ss + 1e-7f);
#pragma unroll
    for (int d = 0; d < DD; ++d) {
        const float vv = coef * s[d];
        if (add_to_dst) dst[idx * DD + d] += vv;
        else            dst[idx * DD + d] = vv;
        if (zero_src)   s_acc[idx * DD + d] = 0.f;
    }
}

__global__ __launch_bounds__(256) void round1_old(const float* __restrict__ x,
                                                  const float* __restrict__ W,
                                                  float* __restrict__ s_acc) {
    const int t = threadIdx.x;
    const int d = t & 15;
    const int bq = t >> 4;
    const int b = blockIdx.y * BT_OLD + bq;
    const int i0 = blockIdx.x * IT_OLD;
    float acc[JJ];
#pragma unroll
    for (int j = 0; j < JJ; ++j) acc[j] = 0.f;
    for (int ii = 0; ii < IT_OLD; ++ii) {
        const int i = i0 + ii;
        const float* xp = x + ((b * II) + i) * KK;
        const float4 xa = *(const float4*)(xp);
        const float4 xb = *(const float4*)(xp + 4);
#pragma unroll
        for (int j = 0; j < JJ; ++j) {
            const float* wp = W + (((j * II + i) * DD + d) * KK);
            const float4 w0 = *(const float4*)(wp);
            const float4 w1 = *(const float4*)(wp + 4);
            acc[j] += w0.x*xa.x + w0.y*xa.y + w0.z*xa.z + w0.w*xa.w
                    + w1.x*xb.x + w1.y*xb.y + w1.z*xb.z + w1.w*xb.w;
        }
    }
#pragma unroll
    for (int j = 0; j < JJ; ++j)
        atomicAdd(&s_acc[(b * JJ + j) * DD + d], acc[j]);
}

__global__ __launch_bounds__(256) void round_old(const float* __restrict__ x,
                                                 const float* __restrict__ W,
                                                 const float* __restrict__ v,
                                                 float* __restrict__ s_acc) {
    const int t = threadIdx.x;
    const int d = t & 15;
    const int bq = t >> 4;
    const int b = blockIdx.y * BT_OLD + bq;
    const int i0 = blockIdx.x * IT_OLD;
    float vr[JJ], acc[JJ];
#pragma unroll
    for (int j = 0; j < JJ; ++j) {
        vr[j] = v[(b * JJ + j) * DD + d];
        acc[j] = 0.f;
    }
    for (int ii = 0; ii < IT_OLD; ++ii) {
        const int i = i0 + ii;
        const float* xp = x + ((b * II) + i) * KK;
        const float4 xa = *(const float4*)(xp);
        const float4 xb = *(const float4*)(xp + 4);
        float U[JJ], Lg[JJ];
#pragma unroll
        for (int j = 0; j < JJ; ++j) {
            const float* wp = W + (((j * II + i) * DD + d) * KK);
            const float4 w0 = *(const float4*)(wp);
            const float4 w1 = *(const float4*)(wp + 4);
            U[j] = w0.x*xa.x + w0.y*xa.y + w0.z*xa.z + w0.w*xa.w
                 + w1.x*xb.x + w1.y*xb.y + w1.z*xb.z + w1.w*xb.w;
            Lg[j] = vr[j] * U[j];
        }
#pragma unroll
        for (int m = 8; m >= 1; m >>= 1) {
#pragma unroll
            for (int j = 0; j < JJ; ++j) Lg[j] += __shfl_xor(Lg[j], m, 64);
        }
        float mx = Lg[0];
#pragma unroll
        for (int j = 1; j < JJ; ++j) mx = fmaxf(mx, Lg[j]);
        float sum = 0.f;
#pragma unroll
        for (int j = 0; j < JJ; ++j) { Lg[j] = __expf(Lg[j] - mx); sum += Lg[j]; }
        const float inv = 1.f / sum;
#pragma unroll
        for (int j = 0; j < JJ; ++j) acc[j] += (Lg[j] * inv) * U[j];
    }
#pragma unroll
    for (int j = 0; j < JJ; ++j)
        atomicAdd(&s_acc[(b * JJ + j) * DD + d], acc[j]);
}

extern "C" void kernel_launch(void* const* d_in, const int* in_sizes, int n_in,
                              void* d_out, int out_size, void* d_ws, size_t ws_size,
                              hipStream_t stream) {
    const float* x = (const float*)d_in[0];   // [B, I, K]
    const float* W = (const float*)d_in[1];   // [J, I, D, K]
    float* out = (float*)d_out;               // [B, J, D]

    float* vT  = (float*)d_ws;                          // 40960 f32
    float* p   = vT + BB * JJ * DD;                     // 16*NCH*2560 f32
    short* xTb = (short*)(p + (size_t)16 * NCH * 2560); // I*B*K bf16
    short* Wb  = xTb + (size_t)II * BB * KK;            // J*I*D*K bf16
    const size_t need = (size_t)(BB * JJ * DD + 16 * NCH * 2560) * 4
                      + ((size_t)II * BB * KK + (size_t)JJ * II * DD * KK) * 2;

    if (ws_size >= need) {
        cast_w_kernel<<<(JJ * II * DD * KK / 8) / 256, 256, 0, stream>>>(W, Wb);
        trans_x_kernel<<<dim3(II / 8, BB / 32), 256, 0, stream>>>(x, xTb);

        dim3 rg(NCH, 4);
        dim3 sg(JJ, 16);
        // round 1: uniform c (1/J folded into squash scale)
        round_mfma<0><<<rg, 256, 0, stream>>>(xTb, Wb, vT, p);
        rs_kernel<0><<<sg, 256, 0, stream>>>(p, vT, out, 0.1f);
        // round 2: logits = v1 . U
        round_mfma<1><<<rg, 256, 0, stream>>>(xTb, Wb, vT, p);
        rs_kernel<1><<<sg, 256, 0, stream>>>(p, vT, out, 1.0f);
        // round 3: logits = (v1+v2) . U
        round_mfma<1><<<rg, 256, 0, stream>>>(xTb, Wb, vT, p);
        rs_kernel<2><<<sg, 256, 0, stream>>>(p, vT, out, 1.0f);
    } else {
        // fallback: round-1 passing path
        float* s_acc = (float*)d_ws;
        float* v_buf = s_acc + BB * JJ * DD;
        const int NS = BB * JJ * DD;
        dim3 rg(II / IT_OLD, BB / BT_OLD);
        zero_kernel<<<(NS + 255) / 256, 256, 0, stream>>>(s_acc, NS);
        round1_old<<<rg, 256, 0, stream>>>(x, W, s_acc);
        squash_old<<<(BB * JJ + 255) / 256, 256, 0, stream>>>(s_acc, v_buf, 0.1f, 0, 1);
        round_old<<<rg, 256, 0, stream>>>(x, W, v_buf, s_acc);
        squash_old<<<(BB * JJ + 255) / 256, 256, 0, stream>>>(s_acc, v_buf, 1.0f, 1, 1);
        round_old<<<rg, 256, 0, stream>>>(x, W, v_buf, s_acc);
        squash_old<<<(BB * JJ + 255) / 256, 256, 0, stream>>>(s_acc, out, 1.0f, 0, 0);
    }
}

// Round 7
// 163.263 us; speedup vs baseline: 1.1562x; 1.1562x over previous
//
#include <hip/hip_runtime.h>
#include <math.h>

// CapsuleLayer dynamic routing, fp32 in/out. B=256, I=2048, K=8, J=10, D=16.
// R7: persistent-kernel fusion. Two dispatches total:
//   prep_kernel: zero barrier counters, cast W->bf16, transpose x->xTb[i,b,k] bf16.
//   caps_kernel: 512 blocks (exactly 2/CU, co-resident), runs R1,rs1,R2,rs2,R3,rs3
//                with 5 software grid barriers (device-scope atomics, G16 pattern).
// Round/rs internals are R5's verbatim (validated, absmax 0.0039):
//   mfma_f32_16x16x32_bf16, C/D col=lane&15=b, row=(lane>>4)*4+reg=d.
//   Round 1 packs 4 i into K=32 (kc=q*8+k -> i_local=q); rounds 2/3 use kc 0..7.
//   Routing logits are linear in accumulated v (round 3 uses v1+v2).
// Residency check via hipOccupancyMaxActiveBlocksPerMultiprocessor (capture-safe
// query, no static guards); falls back to R5's multi-kernel path if < 2 blocks/CU.
//
// ws: cnt i32[64] | vT f32[40960] | p f32[16*128*2560] | xTb bf16 | Wb bf16 (~34.8 MB)

#define BB 256
#define II 2048
#define KK 8
#define JJ 10
#define DD 16
#define NCH 128    // i-chunks of 16
#define NBLK 512   // persistent grid: 2 blocks/CU on 256 CUs

typedef __attribute__((ext_vector_type(4))) float f32x4;
typedef __attribute__((ext_vector_type(8))) short short8;

__device__ __forceinline__ short f2bf(float f) {
    union { float f; unsigned u; } v; v.f = f;
    unsigned r = v.u + 0x7FFFu + ((v.u >> 16) & 1u);   // RNE
    return (short)(r >> 16);
}

// ---------------- prep: zero counters + cast W + transpose x ----------------
__global__ __launch_bounds__(256) void prep_kernel(const float* __restrict__ x,
                                                   const float* __restrict__ W,
                                                   short* __restrict__ xTb,
                                                   short* __restrict__ Wb,
                                                   int* __restrict__ cnt) {
    __shared__ float4 tile[8 * 66];
    const int t = threadIdx.x;
    if (blockIdx.x == 0 && t < 16) cnt[t] = 0;

    // cast W [j,i,d,k] fp32 -> bf16 (k contiguous = A-frag rows); 327680 8-elem rows
    for (int r = blockIdx.x * 256 + t; r < JJ * II * DD; r += NBLK * 256) {
        const float4* src = (const float4*)(W + (size_t)r * 8);
        const float4 a = src[0], b = src[1];
        short8 o;
        o[0] = f2bf(a.x); o[1] = f2bf(a.y); o[2] = f2bf(a.z); o[3] = f2bf(a.w);
        o[4] = f2bf(b.x); o[5] = f2bf(b.y); o[6] = f2bf(b.z); o[7] = f2bf(b.w);
        *(short8*)(Wb + (size_t)r * 8) = o;
    }

    // transpose x [b,i,k] -> xTb [i,b,k] bf16; 2048 tiles (8i x 32b), 4 per block
    for (int tl = blockIdx.x; tl < 2048; tl += NBLK) {
        const int i0 = (tl & 255) * 8, b0 = (tl >> 8) * 32;
        __syncthreads();
        {
            const int lb = t >> 3, li = t & 7;
            const float4* src = (const float4*)(x + ((b0 + lb) * II + (i0 + li)) * KK);
            tile[li * 66 + lb * 2 + 0] = src[0];
            tile[li * 66 + lb * 2 + 1] = src[1];
        }
        __syncthreads();
        {
            const int ri = t >> 5, rb = t & 31;
            const float4 p0 = tile[ri * 66 + rb * 2 + 0];
            const float4 p1 = tile[ri * 66 + rb * 2 + 1];
            short8 o;
            o[0] = f2bf(p0.x); o[1] = f2bf(p0.y); o[2] = f2bf(p0.z); o[3] = f2bf(p0.w);
            o[4] = f2bf(p1.x); o[5] = f2bf(p1.y); o[6] = f2bf(p1.z); o[7] = f2bf(p1.w);
            *(short8*)(xTb + ((size_t)(i0 + ri) * BB + (b0 + rb)) * KK) = o;
        }
    }
}

// ---------------- software grid barrier (device-scope, monotonic) ----------------
__device__ __forceinline__ void gbar(int* cnt, int phase) {
    __syncthreads();
    if (threadIdx.x == 0) {
        __threadfence();   // make this block's global writes device-visible
        __hip_atomic_fetch_add(&cnt[phase], 1, __ATOMIC_RELEASE, __HIP_MEMORY_SCOPE_AGENT);
        while (__hip_atomic_load(&cnt[phase], __ATOMIC_ACQUIRE, __HIP_MEMORY_SCOPE_AGENT) < NBLK)
            __builtin_amdgcn_s_sleep(1);
    }
    __syncthreads();
}

// ---------------- R5 round body (verbatim logic) ----------------
// LDS per buffer: W at j*1024+il*128+d*8 (shorts), x at 10240+il*512+b*8. 14336 shorts.
__device__ __forceinline__ void seg_src_dst(int s, int i0, int b0,
                                            const short* __restrict__ xTb,
                                            const short* __restrict__ Wb,
                                            const short** src, int* dst) {
    if (s < 20) {
        const int j = s >> 1, h = s & 1;
        *src = Wb + ((size_t)(j * II + i0) * DD) * KK + h * 512;
        *dst = j * 1024 + h * 512;
    } else {
        const int il = s - 20;
        *src = xTb + ((size_t)(i0 + il) * BB + b0) * KK;
        *dst = 10240 + il * 512;
    }
}

template <int USE_C>
__device__ __forceinline__ void round_body(short (*L)[14336],
    const short* __restrict__ xTb, const short* __restrict__ Wb,
    const float* __restrict__ vT, float* __restrict__ p, int chunk, int bgroup)
{
    const int t = threadIdx.x;
    const int lane = t & 63, wv = t >> 6;
    const int col = lane & 15, q = lane >> 4;
    const int b0 = bgroup * 64;
    const int bl = wv * 16 + col;
    const int i0 = chunk * 16;

    short8 r0[7], r1[7];
#pragma unroll
    for (int n = 0; n < 7; ++n) {
        const int s = wv + n * 4;
        const short* src; int dst;
        seg_src_dst(s, i0, b0, xTb, Wb, &src, &dst);
        r0[n] = *(const short8*)(src + lane * 8);
        seg_src_dst(s, i0 + 8, b0, xTb, Wb, &src, &dst);
        r1[n] = *(const short8*)(src + lane * 8);
    }
#pragma unroll
    for (int n = 0; n < 7; ++n) {
        const int s = wv + n * 4;
        const short* src; int dst;
        seg_src_dst(s, i0, b0, xTb, Wb, &src, &dst);
        *(short8*)(&L[0][dst + lane * 8]) = r0[n];
    }
    __syncthreads();

    f32x4 sfrag[JJ];
#pragma unroll
    for (int j = 0; j < JJ; ++j) sfrag[j] = (f32x4){0.f, 0.f, 0.f, 0.f};

    float vfrag[JJ][4];
    if (USE_C) {
#pragma unroll
        for (int j = 0; j < JJ; ++j)
#pragma unroll
            for (int r = 0; r < 4; ++r)
                vfrag[j][r] = vT[(j * DD + q * 4 + r) * BB + b0 + bl];
    }

#pragma unroll
    for (int sc = 0; sc < 2; ++sc) {
        const short* Lb = L[sc];
        if (USE_C) {
            for (int il = 0; il < 8; ++il) {
                const short8 z = (short8){0, 0, 0, 0, 0, 0, 0, 0};
                short8 Bf = z;
                if (q == 0) Bf = *(const short8*)(&Lb[10240 + il * 512 + bl * 8]);
                f32x4 U[JJ];
                float Lg[JJ];
#pragma unroll
                for (int j = 0; j < JJ; ++j) {
                    short8 Aj = z;
                    if (q == 0) Aj = *(const short8*)(&Lb[j * 1024 + il * 128 + col * 8]);
                    U[j] = __builtin_amdgcn_mfma_f32_16x16x32_bf16(
                        Aj, Bf, (f32x4){0.f, 0.f, 0.f, 0.f}, 0, 0, 0);
                    Lg[j] = vfrag[j][0] * U[j][0] + vfrag[j][1] * U[j][1]
                          + vfrag[j][2] * U[j][2] + vfrag[j][3] * U[j][3];
                }
#pragma unroll
                for (int j = 0; j < JJ; ++j) {   // reduce over the 4 d-quads
                    Lg[j] += __shfl_xor(Lg[j], 16, 64);
                    Lg[j] += __shfl_xor(Lg[j], 32, 64);
                }
                float sum = 0.f;   // |logit| O(1): no max-subtraction needed
#pragma unroll
                for (int j = 0; j < JJ; ++j) { Lg[j] = __expf(Lg[j]); sum += Lg[j]; }
                const float inv = __builtin_amdgcn_rcpf(sum);
#pragma unroll
                for (int j = 0; j < JJ; ++j) {
                    const float c = Lg[j] * inv;
#pragma unroll
                    for (int r = 0; r < 4; ++r) sfrag[j][r] += c * U[j][r];
                }
            }
        } else {
            // round 1: sum_i U; pack 4 i per MFMA: kc = q*8+k -> i_local = q
#pragma unroll
            for (int g = 0; g < 2; ++g) {
                const int il = g * 4 + q;
                const short8 Bf = *(const short8*)(&Lb[10240 + il * 512 + bl * 8]);
#pragma unroll
                for (int j = 0; j < JJ; ++j) {
                    const short8 Aj = *(const short8*)(&Lb[j * 1024 + il * 128 + col * 8]);
                    sfrag[j] = __builtin_amdgcn_mfma_f32_16x16x32_bf16(Aj, Bf, sfrag[j], 0, 0, 0);
                }
            }
        }
        if (sc == 0) {
#pragma unroll
            for (int n = 0; n < 7; ++n) {
                const int s = wv + n * 4;
                const short* src; int dst;
                seg_src_dst(s, i0 + 8, b0, xTb, Wb, &src, &dst);
                *(short8*)(&L[1][dst + lane * 8]) = r1[n];
            }
            __syncthreads();
        }
    }

    float* pp = p + ((size_t)(bgroup * 4 + wv) * NCH + chunk) * (JJ * 256);
#pragma unroll
    for (int j = 0; j < JJ; ++j)
        *(f32x4*)(pp + (j * 64 + lane) * 4) = sfrag[j];
}

// ---------------- R5 rs body (verbatim logic) ----------------
template <int MODE>
__device__ __forceinline__ void rs_body(float* red, float* cf,
    const float* __restrict__ p, float* __restrict__ vT, float* __restrict__ out,
    float scale, int j, int bt)
{
    const int t = threadIdx.x;
    const int d = t >> 4, bc = t & 15;
    const int lane = (d >> 2) * 16 + bc, r = d & 3;

    const float* pp = p + (size_t)bt * NCH * (JJ * 256) + j * 256 + lane * 4 + r;
    float sum = 0.f;
#pragma unroll 8
    for (int ch = 0; ch < NCH; ++ch) sum += pp[(size_t)ch * (JJ * 256)];
    const float s = sum * scale;

    red[t] = s;
    __syncthreads();
    if (t < 16) {
        float ss = 0.f;
#pragma unroll
        for (int dd = 0; dd < DD; ++dd) {
            const float v = red[dd * 16 + t];
            ss += v * v;
        }
        cf[t] = ss / (1.f + ss) / sqrtf(ss + 1e-7f);
    }
    __syncthreads();
    const float v = cf[bc] * s;
    if (MODE == 0) vT[(j * DD + d) * BB + bt * 16 + bc] = v;
    if (MODE == 1) vT[(j * DD + d) * BB + bt * 16 + bc] += v;
    if (MODE == 2) out[((bt * 16 + bc) * JJ + j) * DD + d] = v;
}

// ---------------- persistent fused kernel ----------------
__global__ __launch_bounds__(256, 2) void caps_kernel(
    const short* __restrict__ xTb, const short* __restrict__ Wb,
    float* __restrict__ vT, float* __restrict__ p, float* __restrict__ out,
    int* __restrict__ cnt)
{
    __shared__ short Ls[2][14336];
    float* red = (float*)&Ls[0][0];
    float* cf  = red + 256;
    const int bid = blockIdx.x;
    const int chunk = bid & (NCH - 1), bgroup = bid >> 7;
    const int rj = bid >> 4, rbt = bid & 15;

    round_body<0>(Ls, xTb, Wb, vT, p, chunk, bgroup);
    gbar(cnt, 0);
    if (bid < JJ * 16) rs_body<0>(red, cf, p, vT, out, 0.1f, rj, rbt);
    gbar(cnt, 1);
    round_body<1>(Ls, xTb, Wb, vT, p, chunk, bgroup);
    gbar(cnt, 2);
    if (bid < JJ * 16) rs_body<1>(red, cf, p, vT, out, 1.0f, rj, rbt);
    gbar(cnt, 3);
    round_body<1>(Ls, xTb, Wb, vT, p, chunk, bgroup);
    gbar(cnt, 4);
    if (bid < JJ * 16) rs_body<2>(red, cf, p, vT, out, 1.0f, rj, rbt);
}

// ---------------- R5 multi-kernel fallback wrappers ----------------
template <int USE_C>
__global__ __launch_bounds__(256) void round_mfma_k(const short* __restrict__ xTb,
                                                    const short* __restrict__ Wb,
                                                    const float* __restrict__ vT,
                                                    float* __restrict__ p) {
    __shared__ short Ls[2][14336];
    round_body<USE_C>(Ls, xTb, Wb, vT, p, blockIdx.x, blockIdx.y);
}

template <int MODE>
__global__ __launch_bounds__(256) void rs_k(const float* __restrict__ p,
                                            float* __restrict__ vT,
                                            float* __restrict__ out, float scale) {
    __shared__ float red[256 + 16];
    rs_body<MODE>(red, red + 256, p, vT, out, scale, blockIdx.x, blockIdx.y);
}

extern "C" void kernel_launch(void* const* d_in, const int* in_sizes, int n_in,
                              void* d_out, int out_size, void* d_ws, size_t ws_size,
                              hipStream_t stream) {
    const float* x = (const float*)d_in[0];   // [B, I, K]
    const float* W = (const float*)d_in[1];   // [J, I, D, K]
    float* out = (float*)d_out;               // [B, J, D]

    int*   cnt = (int*)d_ws;                            // 64 i32
    float* vT  = (float*)d_ws + 64;                     // 40960 f32
    float* p   = vT + BB * JJ * DD;                     // 16*NCH*2560 f32
    short* xTb = (short*)(p + (size_t)16 * NCH * 2560); // I*B*K bf16
    short* Wb  = xTb + (size_t)II * BB * KK;            // J*I*D*K bf16

    // residency check (pure query, capture-safe): persistent kernel needs 2 blocks/CU
    int occ = 0;
    hipError_t oe = hipOccupancyMaxActiveBlocksPerMultiprocessor(&occ, caps_kernel, 256, 0);

    prep_kernel<<<NBLK, 256, 0, stream>>>(x, W, xTb, Wb, cnt);

    if (oe == hipSuccess && occ >= 2) {
        caps_kernel<<<NBLK, 256, 0, stream>>>(xTb, Wb, vT, p, out, cnt);
    } else {
        dim3 rg(NCH, 4);
        dim3 sg(JJ, 16);
        round_mfma_k<0><<<rg, 256, 0, stream>>>(xTb, Wb, vT, p);
        rs_k<0><<<sg, 256, 0, stream>>>(p, vT, out, 0.1f);
        round_mfma_k<1><<<rg, 256, 0, stream>>>(xTb, Wb, vT, p);
        rs_k<1><<<sg, 256, 0, stream>>>(p, vT, out, 1.0f);
        round_mfma_k<1><<<rg, 256, 0, stream>>>(xTb, Wb, vT, p);
        rs_k<2><<<sg, 256, 0, stream>>>(p, vT, out, 1.0f);
    }
}